// Round 7
// baseline (1056.149 us; speedup 1.0000x reference)
//
#include <hip/hip_runtime.h>
#include <math.h>

#define HIDDEN 4096
#define MULT 4
#define HCD 16384      // MULT*HIDDEN
#define MIX 24
#define BB 4096

#define NSLICE 16      // logit d-slices
#define DSLICE 1024    // HCD / NSLICE

// ---------- K0: transpose fn[24][16384] -> fnT[16384][24] ----------
__global__ __launch_bounds__(256) void k_transpose_fn(const float* __restrict__ fn,
                                                      float* __restrict__ fnT) {
    const int d = blockIdx.x * 256 + threadIdx.x;   // 0..16383
    float v[MIX];
#pragma unroll
    for (int m = 0; m < MIX; ++m) v[m] = fn[(size_t)m * HCD + d];
    float4* dst = (float4*)(fnT + (size_t)d * MIX);
#pragma unroll
    for (int m4 = 0; m4 < MIX / 4; ++m4)
        dst[m4] = make_float4(v[4*m4+0], v[4*m4+1], v[4*m4+2], v[4*m4+3]);
}

// ---------- K1: residual_cur + ssq. Barrier-free streaming. ----------
// grid = 4096 blocks (one per batch row) x 256 threads.
// comb/pm are wave-uniform (b = blockIdx) -> s_loads, zero VGPR cost.
// Each thread covers 4 chunks of float4 -> full 4096-h row per block.
__global__ __launch_bounds__(256) void k_res(
        const float* __restrict__ x_prev, const float* __restrict__ res_prev,
        const float* __restrict__ pm_prev, const float* __restrict__ comb_prev,
        float* __restrict__ res_cur, float* __restrict__ part_sq)
{
    const int b   = blockIdx.x;
    const int tid = threadIdx.x;
    const int wid = tid >> 6, lane = tid & 63;

    float comb[MULT][MULT], pm[MULT];     // uniform -> SGPR
#pragma unroll
    for (int i = 0; i < MULT; ++i) {
        pm[i] = pm_prev[(size_t)b * MULT + i];
#pragma unroll
        for (int j = 0; j < MULT; ++j)
            comb[i][j] = comb_prev[(size_t)b * 16 + i * 4 + j];
    }

    float ssq = 0.f;
    const float* xb = x_prev   + (size_t)b * HIDDEN;
    const float* rb = res_prev + (size_t)b * MULT * HIDDEN;
    float*       ob = res_cur  + (size_t)b * MULT * HIDDEN;

#pragma unroll
    for (int c = 0; c < 4; ++c) {
        const int h = (c * 256 + tid) * 4;            // 0..4092
        const float4 xv = *(const float4*)(xb + h);
        float4 rv[MULT];
#pragma unroll
        for (int j = 0; j < MULT; ++j)
            rv[j] = *(const float4*)(rb + (size_t)j * HIDDEN + h);
#pragma unroll
        for (int i = 0; i < MULT; ++i) {
            float4 r;
            r.x = pm[i] * xv.x; r.y = pm[i] * xv.y;
            r.z = pm[i] * xv.z; r.w = pm[i] * xv.w;
#pragma unroll
            for (int j = 0; j < MULT; ++j) {
                r.x += comb[i][j] * rv[j].x; r.y += comb[i][j] * rv[j].y;
                r.z += comb[i][j] * rv[j].z; r.w += comb[i][j] * rv[j].w;
            }
            *(float4*)(ob + (size_t)i * HIDDEN + h) = r;
            ssq += r.x*r.x + r.y*r.y + r.z*r.z + r.w*r.w;
        }
    }

    // block-reduce ssq (one barrier at kernel end, harmless)
#pragma unroll
    for (int off = 32; off; off >>= 1) ssq += __shfl_down(ssq, off);
    __shared__ float sred[4];
    if (lane == 0) sred[wid] = ssq;
    __syncthreads();
    if (tid == 0) part_sq[b] = sred[0] + sred[1] + sred[2] + sred[3];
}

// ---------- K2: partial logits. Barrier-free GEMV-24 over res_cur (L3-warm). ----------
// grid = 256 blocks x 256 threads = 1024 waves. Wave g = (rg, sl):
// lane = row within 64-row group (NO duplicated compute), d wave-uniform ->
// fnT rows arrive as s_load broadcasts (SGPR operand in the FMAs).
__global__ __launch_bounds__(256) void k_logit(
        const float* __restrict__ res_cur, const float* __restrict__ fnT,
        float* __restrict__ part_lg)
{
    const int wid  = threadIdx.x >> 6, lane = threadIdx.x & 63;
    const int g    = blockIdx.x * 4 + wid;   // 0..1023
    const int rg   = g >> 4;                 // row group 0..63
    const int sl   = g & 15;                 // d-slice 0..15
    const int b    = rg * 64 + lane;

    const float* rp  = res_cur + (size_t)b * HCD + (size_t)sl * DSLICE;
    const float* fp0 = fnT + (size_t)sl * DSLICE * MIX;

    float acc[MIX];
#pragma unroll
    for (int m = 0; m < MIX; ++m) acc[m] = 0.f;

#pragma unroll 4
    for (int ds = 0; ds < DSLICE / 4; ++ds) {   // 256 iters
        const float4 v  = *(const float4*)(rp + ds * 4);
        const float* fp = fp0 + (size_t)ds * 4 * MIX;   // wave-uniform
#pragma unroll
        for (int m = 0; m < MIX; ++m) acc[m] += v.x * fp[m];
#pragma unroll
        for (int m = 0; m < MIX; ++m) acc[m] += v.y * fp[MIX + m];
#pragma unroll
        for (int m = 0; m < MIX; ++m) acc[m] += v.z * fp[2 * MIX + m];
#pragma unroll
        for (int m = 0; m < MIX; ++m) acc[m] += v.w * fp[3 * MIX + m];
    }

    float* dst = part_lg + ((size_t)sl * BB + b) * MIX;
#pragma unroll
    for (int m4 = 0; m4 < 6; ++m4)
        *(float4*)(dst + m4 * 4) =
            make_float4(acc[4*m4+0], acc[4*m4+1], acc[4*m4+2], acc[4*m4+3]);
}

// ---------- K3: per-row finalize + layer_input (fused; verified round 6) ----------
__global__ __launch_bounds__(256) void k_post(
        const float* __restrict__ part_lg, const float* __restrict__ part_sq,
        const float* __restrict__ basep, const float* __restrict__ scale,
        const float* __restrict__ res_cur,
        float* __restrict__ post_mix, float* __restrict__ comb_out,
        float* __restrict__ layer_in)
{
    const int b   = blockIdx.x;       // row 0..4095
    const int tid = threadIdx.x;
    __shared__ float red[MIX + 1];    // 24 logit sums + ssq
    __shared__ float hp_s[4];

    if (tid < MIX) {
        float s = 0.f;
#pragma unroll
        for (int w = 0; w < NSLICE; ++w)
            s += part_lg[((size_t)w * BB + b) * MIX + tid];
        red[tid] = s;
    } else if (tid == MIX) {
        red[MIX] = part_sq[b];
    }
    __syncthreads();

    if (tid == 0) {
        const float rms = sqrtf(red[MIX] * (1.0f / (float)HCD) + 1e-6f);
        const float inv = 1.0f / rms;
        const float s0 = scale[0], s1 = scale[1], s2 = scale[2];

        float pre[4], post[4], rr[16];
#pragma unroll
        for (int i = 0; i < 4; ++i)  pre[i]  = red[i]     * inv * s0 + basep[i];
#pragma unroll
        for (int i = 0; i < 4; ++i)  post[i] = red[4 + i] * inv * s1 + basep[4 + i];
#pragma unroll
        for (int k = 0; k < 16; ++k) rr[k]   = red[8 + k] * inv * s2 + basep[8 + k];

        // softmax (stable) -> hp_s (consumed in-block)
        const float mx = fmaxf(fmaxf(pre[0], pre[1]), fmaxf(pre[2], pre[3]));
        float e[4], es = 0.f;
#pragma unroll
        for (int i = 0; i < 4; ++i) { e[i] = expf(pre[i] - mx); es += e[i]; }
        const float esr = 1.0f / es;
#pragma unroll
        for (int i = 0; i < 4; ++i) hp_s[i] = e[i] * esr;

        // sigmoid -> post_mix_cur
        float4 pmv = make_float4(1.f/(1.f+expf(-post[0])), 1.f/(1.f+expf(-post[1])),
                                 1.f/(1.f+expf(-post[2])), 1.f/(1.f+expf(-post[3])));
        *(float4*)(post_mix + (size_t)b * 4) = pmv;

        // Sinkhorn-Knopp, 10 iters (reciprocal-multiply, verified rounds 5/6)
        float M[16];
#pragma unroll
        for (int k = 0; k < 16; ++k) M[k] = expf(rr[k]);
#pragma unroll 1
        for (int it = 0; it < 10; ++it) {
#pragma unroll
            for (int i = 0; i < 4; ++i) {
                const float rs = 1.0f /
                    (M[i*4+0] + M[i*4+1] + M[i*4+2] + M[i*4+3] + 1e-6f);
#pragma unroll
                for (int j = 0; j < 4; ++j) M[i*4+j] *= rs;
            }
#pragma unroll
            for (int j = 0; j < 4; ++j) {
                const float cs = 1.0f /
                    (M[j] + M[4+j] + M[8+j] + M[12+j] + 1e-6f);
#pragma unroll
                for (int i = 0; i < 4; ++i) M[i*4+j] *= cs;
            }
        }
#pragma unroll
        for (int m4 = 0; m4 < 4; ++m4)
            *(float4*)(comb_out + (size_t)b * 16 + m4 * 4) =
                make_float4(M[4*m4+0], M[4*m4+1], M[4*m4+2], M[4*m4+3]);
    }
    __syncthreads();

    // layer_input[b,:] = sum_i hp[i] * res_cur[b,i,:]
    const float h0 = hp_s[0], h1 = hp_s[1], h2 = hp_s[2], h3 = hp_s[3];
    const float* rp = res_cur + (size_t)b * (MULT * HIDDEN);
    float* op = layer_in + (size_t)b * HIDDEN;
#pragma unroll
    for (int c = 0; c < 4; ++c) {
        const int c4 = (tid + c * 256) * 4;   // float element offset, 0..4092
        const float4 v0 = *(const float4*)(rp + 0 * HIDDEN + c4);
        const float4 v1 = *(const float4*)(rp + 1 * HIDDEN + c4);
        const float4 v2 = *(const float4*)(rp + 2 * HIDDEN + c4);
        const float4 v3 = *(const float4*)(rp + 3 * HIDDEN + c4);
        float4 o;
        o.x = h0*v0.x + h1*v1.x + h2*v2.x + h3*v3.x;
        o.y = h0*v0.y + h1*v1.y + h2*v2.y + h3*v3.y;
        o.z = h0*v0.z + h1*v1.z + h2*v2.z + h3*v3.z;
        o.w = h0*v0.w + h1*v1.w + h2*v2.w + h3*v3.w;
        *(float4*)(op + c4) = o;
    }
}

extern "C" void kernel_launch(void* const* d_in, const int* in_sizes, int n_in,
                              void* d_out, int out_size, void* d_ws, size_t ws_size,
                              hipStream_t stream) {
    const float* x_prev    = (const float*)d_in[0];
    const float* res_prev  = (const float*)d_in[1];
    const float* pm_prev   = (const float*)d_in[2];
    const float* comb_prev = (const float*)d_in[3];
    const float* fn        = (const float*)d_in[4];
    const float* base      = (const float*)d_in[5];
    const float* scale     = (const float*)d_in[6];

    float* out = (float*)d_out;
    float* res_cur  = out;                                   // 4096*4*4096
    float* post_mix = out + 67108864;                        // 4096*4
    float* comb_out = out + 67108864 + 16384;                // 4096*16
    float* layer_in = out + 67108864 + 16384 + 65536;        // 4096*4096

    float* ws = (float*)d_ws;
    float* fnT     = ws;                                     // 393,216 floats
    float* part_lg = ws + 393216;                            // 16*4096*24 = 1,572,864
    float* part_sq = ws + 393216 + 1572864;                  // 4096

    k_transpose_fn<<<HCD / 256, 256, 0, stream>>>(fn, fnT);
    k_res<<<BB, 256, 0, stream>>>(x_prev, res_prev, pm_prev, comb_prev,
                                  res_cur, part_sq);
    k_logit<<<256, 256, 0, stream>>>(res_cur, fnT, part_lg);
    k_post<<<BB, 256, 0, stream>>>(part_lg, part_sq, base, scale, res_cur,
                                   post_mix, comb_out, layer_in);
}